// Round 1
// baseline (6435.281 us; speedup 1.0000x reference)
//
#include <hip/hip_runtime.h>
#include <hip/hip_bf16.h>

typedef unsigned int u32;
typedef unsigned short u16;

// Geometry: B=32, IC=1, N=64, KN=128, KS=65, PAD=16, R=8, LAT=32, HW=32
#define KSP 68          // kx row padded 65 -> 68 (16B-aligned f32 rows)
#define XP_R 100        // padded image rows (96 used + slack)
#define XP_C 104        // padded image cols (96 used + slack)

// d_out element offsets (fp32)
#define OUT_ATTN 0
#define OUT_QTR  262144
#define OUT_PR   524288
#define OUT_AS   524296
#define OUT_OFF  786440
#define OUT_TH   786448
#define OUT_Z    1310736

__device__ const float OFFS[8] = {
  0.0f,
  0.78539816339744830961f,
  1.57079632679489661923f,
  2.35619449019234492885f,
  3.14159265358979323846f,
 -2.35619449019234492885f,
 -1.57079632679489661923f,
 -0.78539816339744830961f
};

__device__ __forceinline__ float leaky_(float v){ return v >= 0.0f ? v : 0.01f*v; }

__device__ __forceinline__ u16 f2bf(float f){
  u32 x = __float_as_uint(f);
  u32 r = (x + 0x7FFFu + ((x >> 16) & 1u)) >> 16;   // RNE
  return (u16)r;
}

// ---------------- pad: x(32,64,64) -> xp(32,100,104) zero-padded ----------------
__global__ void pad_kernel(const float* __restrict__ x, float* __restrict__ xp){
  int idx = blockIdx.x*256 + threadIdx.x;
  if (idx >= 32*XP_R*XP_C) return;
  int c  = idx % XP_C;
  int t  = idx / XP_C;
  int rr = t % XP_R;
  int b  = t / XP_R;
  int iy = rr - 16, ix = c - 16;
  float v = 0.0f;
  if (iy >= 0 && iy < 64 && ix >= 0 && ix < 64) v = x[(b*64 + iy)*64 + ix];
  xp[idx] = v;
}

// ---------------- rotate: w1(128,65,65) -> tw(1024,65,KSP), oc = o*8+rot ----------------
__global__ __launch_bounds__(256) void rotate_kernel(const float* __restrict__ w1, float* __restrict__ tw){
  __shared__ float wsh[4225];
  int oc = blockIdx.x;          // 0..1023
  int o = oc >> 3, rot = oc & 7;
  for (int i = threadIdx.x; i < 4225; i += 256) wsh[i] = w1[o*4225 + i];
  __syncthreads();
  float th  = 0.78539816339744830961f * (float)rot;   // 2*pi/8 * rot (f32, matches jnp)
  float cth = cosf(th), sth = sinf(th);
  for (int t = threadIdx.x; t < 65*KSP; t += 256){
    int i = t / KSP, j = t % KSP;   // i = row(y), j = col(x)
    float val = 0.0f;
    if (j < 65){
      float yy = (2.0f*(float)i + 1.0f)/65.0f - 1.0f;
      float xx = (2.0f*(float)j + 1.0f)/65.0f - 1.0f;
      float xs  =  cth*xx + sth*yy;
      float ysv = -sth*xx + cth*yy;
      float px = ((xs  + 1.0f)*65.0f - 1.0f)*0.5f;
      float py = ((ysv + 1.0f)*65.0f - 1.0f)*0.5f;
      float x0 = floorf(px), y0 = floorf(py);
      float wx = px - x0, wy = py - y0;
      auto samp = [&](float yf, float xf)->float{
        bool valid = (yf >= 0.0f) && (yf < 65.0f) && (xf >= 0.0f) && (xf < 65.0f);
        int yc = (int)fminf(fmaxf(yf, 0.0f), 64.0f);
        int xc = (int)fminf(fmaxf(xf, 0.0f), 64.0f);
        return valid ? wsh[yc*65 + xc] : 0.0f;
      };
      val = samp(y0,      x0     )*(1.0f-wy)*(1.0f-wx)
          + samp(y0,      x0+1.0f)*(1.0f-wy)*wx
          + samp(y0+1.0f, x0     )*wy*(1.0f-wx)
          + samp(y0+1.0f, x0+1.0f)*wy*wx;
    }
    tw[(oc*65 + i)*KSP + j] = val;
  }
}

// ---------------- conv: y[(b,r,pix)][kn] bf16, block = (b, kn-tile16, r, oy-tile8) ----------------
__global__ __launch_bounds__(256) void conv_kernel(const float* __restrict__ xp,
                                                   const float* __restrict__ tw,
                                                   u32* __restrict__ ys){
  __shared__ float xsh[72*104];
  int bid = blockIdx.x;
  int b   = bid >> 8;           // 32
  int rem = bid & 255;
  int r0  = rem & 7;            // rotation
  int knt = (rem >> 3) & 7;     // kn tile: kn0 = knt*16
  int oyt = rem >> 6;           // 0..3 : oy0 = oyt*8
  {
    const float4* src = (const float4*)(xp + (b*XP_R + oyt*8)*XP_C);
    float4* dst = (float4*)xsh;
    for (int i = threadIdx.x; i < 72*104/4; i += 256) dst[i] = src[i];
  }
  __syncthreads();
  int oy_l = threadIdx.x >> 5, ox = threadIdx.x & 31;
  float acc[16];
#pragma unroll
  for (int o = 0; o < 16; ++o) acc[o] = 0.0f;
  // filter row for acc[o]: oc = (knt*16+o)*8 + r0
  const float* wb = tw + ((size_t)((knt*16)*8 + r0))*(65*KSP);
  const int OSTR = 8*65*KSP;
  for (int ky = 0; ky < 65; ++ky){
    const float* xr = &xsh[(oy_l + ky)*104 + ox];
    for (int kxc = 0; kxc < 64; kxc += 16){
      float xv[16];
#pragma unroll
      for (int i = 0; i < 16; ++i) xv[i] = xr[kxc + i];
#pragma unroll
      for (int o = 0; o < 16; ++o){
        const float* wr_ = wb + o*OSTR + ky*KSP + kxc;   // wave-uniform -> s_load
#pragma unroll
        for (int i = 0; i < 16; ++i) acc[o] += xv[i]*wr_[i];
      }
    }
    float xt = xr[64];
#pragma unroll
    for (int o = 0; o < 16; ++o) acc[o] += xt * wb[o*OSTR + ky*KSP + 64];
  }
  int pix = (oyt*8 + oy_l)*32 + ox;
  u32 pk[8];
#pragma unroll
  for (int j = 0; j < 8; ++j){
    u32 lo = f2bf(acc[2*j]);
    u32 hi = f2bf(acc[2*j+1]);
    pk[j] = lo | (hi << 16);
  }
  // ys element offset = ((b*8+r0)*1024 + pix)*128 + knt*16   (bf16), store as 2x uint4
  size_t eoff = (((size_t)(b*8 + r0)*1024 + (size_t)pix)*128 + (size_t)knt*16) / 2;
  uint4* d4 = (uint4*)(ys + eoff);
  d4[0] = make_uint4(pk[0],pk[1],pk[2],pk[3]);
  d4[1] = make_uint4(pk[4],pk[5],pk[6],pk[7]);
}

// ---------------- mix: per row rho=(b,r,pix): xa -> h -> {z, attn, theta} ----------------
__global__ __launch_bounds__(256) void mix_kernel(const u16* __restrict__ ys,
    const float* __restrict__ b1, const float* __restrict__ w2, const float* __restrict__ b2,
    const float* __restrict__ wa, const float* __restrict__ ba,
    const float* __restrict__ wr, const float* __restrict__ br,
    const float* __restrict__ wz, const float* __restrict__ bz,
    float* __restrict__ out){
  int rho = blockIdx.x*256 + threadIdx.x;   // 0..262143, = (b*8+r)*1024 + pix
  int pix = rho & 1023;
  int r   = (rho >> 10) & 7;
  int b   = rho >> 13;
  const u16* yrow = ys + (size_t)rho*128;
  float zacc[67];
#pragma unroll
  for (int c = 0; c < 67; ++c) zacc[c] = 0.0f;
#pragma unroll 1
  for (int half = 0; half < 2; ++half){
    float hacc[64];
#pragma unroll
    for (int o = 0; o < 64; ++o) hacc[o] = 0.0f;
#pragma unroll 1
    for (int knc = 0; knc < 128; knc += 16){
      float xv[16];
      const uint4* yp = (const uint4*)(yrow + knc);
      uint4 v0 = yp[0], v1 = yp[1];
      u32 vv[8] = {v0.x,v0.y,v0.z,v0.w,v1.x,v1.y,v1.z,v1.w};
#pragma unroll
      for (int j = 0; j < 8; ++j){
        float lo = __uint_as_float(vv[j] << 16);
        float hi = __uint_as_float(vv[j] & 0xFFFF0000u);
        xv[2*j]   = leaky_(lo + b1[knc + 2*j]);
        xv[2*j+1] = leaky_(hi + b1[knc + 2*j + 1]);
      }
#pragma unroll
      for (int o = 0; o < 64; ++o){
        const float* wrow = w2 + (half*64 + o)*128 + knc;   // uniform -> s_load
#pragma unroll
        for (int i = 0; i < 16; ++i) hacc[o] += wrow[i]*xv[i];
      }
    }
#pragma unroll
    for (int o = 0; o < 64; ++o) hacc[o] = leaky_(hacc[o] + b2[half*64 + o]);
#pragma unroll
    for (int c = 0; c < 64; ++c){
      const float* wrow = wz + c*128 + half*64;
      float s = 0.0f;
#pragma unroll
      for (int o = 0; o < 64; ++o) s += wrow[o]*hacc[o];
      zacc[c] += s;
    }
    {
      const float* wrow = wa + half*64;
      float s = 0.0f;
#pragma unroll
      for (int o = 0; o < 64; ++o) s += wrow[o]*hacc[o];
      zacc[64] += s;
    }
    {
      const float* wrow = wr + half*64;
      float s = 0.0f;
#pragma unroll
      for (int o = 0; o < 64; ++o) s += wrow[o]*hacc[o];
      zacc[65] += s;
    }
    {
      const float* wrow = wr + 128 + half*64;
      float s = 0.0f;
#pragma unroll
      for (int o = 0; o < 64; ++o) s += wrow[o]*hacc[o];
      zacc[66] += s;
    }
  }
  // z[b][c][r][pix]
  float* zout = out + OUT_Z + (size_t)b*524288 + (size_t)r*1024 + pix;
#pragma unroll
  for (int c = 0; c < 64; ++c) zout[(size_t)c*8192] = zacc[c] + bz[c];
  float qn = OFFS[r] / 3.14159265358979323846f;
  float pr = -0.5f*qn*qn - 1.14472988584940017414f - 0.91893853320467274178f;
  out[OUT_ATTN + rho] = zacc[64] + ba[0] + pr;
  out[OUT_TH + ((size_t)b*2 + 0)*8192 + (size_t)r*1024 + pix] = zacc[65] + br[0] + OFFS[r];
  out[OUT_TH + ((size_t)b*2 + 1)*8192 + (size_t)r*1024 + pix] = zacc[66] + br[1];
}

// ---------------- softmax: per batch b, over 8192 attn values ----------------
__global__ __launch_bounds__(256) void softmax_kernel(const float* __restrict__ gumbel, float* __restrict__ out){
  __shared__ float a[8192];
  __shared__ float red[256];
  const int b = blockIdx.x, t = threadIdx.x;
  const float* attn = out + OUT_ATTN + (size_t)b*8192;
  float m = -3.0e38f;
  for (int i = t; i < 8192; i += 256){ float v = attn[i]; a[i] = v; m = fmaxf(m, v); }
  red[t] = m; __syncthreads();
#pragma unroll
  for (int s = 128; s > 0; s >>= 1){ if (t < s) red[t] = fmaxf(red[t], red[t+s]); __syncthreads(); }
  m = red[0]; __syncthreads();
  float s1 = 0.0f;
  for (int i = t; i < 8192; i += 256) s1 += expf(a[i] - m);
  red[t] = s1; __syncthreads();
#pragma unroll
  for (int s = 128; s > 0; s >>= 1){ if (t < s) red[t] += red[t+s]; __syncthreads(); }
  float lse = m + logf(red[0]);
  __syncthreads();
  float* q = out + OUT_QTR + (size_t)b*8192;
  for (int i = t; i < 8192; i += 256) q[i] = a[i] - lse;
  const float* g = gumbel + (size_t)b*8192;
  float m2 = -3.0e38f;
  for (int i = t; i < 8192; i += 256){ float v = a[i] + g[i]; a[i] = v; m2 = fmaxf(m2, v); }
  __syncthreads();
  red[t] = m2; __syncthreads();
#pragma unroll
  for (int s = 128; s > 0; s >>= 1){ if (t < s) red[t] = fmaxf(red[t], red[t+s]); __syncthreads(); }
  m2 = red[0]; __syncthreads();
  float s2 = 0.0f;
  for (int i = t; i < 8192; i += 256) s2 += expf(a[i] - m2);
  red[t] = s2; __syncthreads();
#pragma unroll
  for (int s = 128; s > 0; s >>= 1){ if (t < s) red[t] += red[t+s]; __syncthreads(); }
  float inv = 1.0f/red[0];
  float* as_ = out + OUT_AS + (size_t)b*8192;
  for (int i = t; i < 8192; i += 256) as_[i] = expf(a[i] - m2)*inv;
}

// ---------------- tiny: p_r and offsets ----------------
__global__ void tiny_kernel(float* __restrict__ out){
  int t = threadIdx.x;
  if (t < 8){
    float off = OFFS[t];
    out[OUT_OFF + t] = off;
    float qn = off / 3.14159265358979323846f;
    out[OUT_PR + t] = -0.5f*qn*qn - 1.14472988584940017414f - 0.91893853320467274178f;
  }
}

extern "C" void kernel_launch(void* const* d_in, const int* in_sizes, int n_in,
                              void* d_out, int out_size, void* d_ws, size_t ws_size,
                              hipStream_t stream){
  const float* x      = (const float*)d_in[0];
  const float* w1     = (const float*)d_in[1];
  const float* b1     = (const float*)d_in[2];
  const float* w2     = (const float*)d_in[3];
  const float* b2     = (const float*)d_in[4];
  const float* wa     = (const float*)d_in[5];
  const float* ba     = (const float*)d_in[6];
  const float* wr     = (const float*)d_in[7];
  const float* br     = (const float*)d_in[8];
  const float* wz     = (const float*)d_in[9];
  const float* bz     = (const float*)d_in[10];
  const float* gumbel = (const float*)d_in[11];
  float* out = (float*)d_out;

  // workspace layout
  float* tw = (float*)d_ws;                         // 1024*65*68 f32 = 18,104,320 B
  float* xp = tw + (size_t)1024*65*KSP;             // 32*100*104 f32 = 1,331,200 B
  u16*   ysb = (u16*)(xp + (size_t)32*XP_R*XP_C);   // 262144*128 bf16 = 67,108,864 B
  // total ~86.5 MB

  pad_kernel    <<<1300, 256, 0, stream>>>(x, xp);
  rotate_kernel <<<1024, 256, 0, stream>>>(w1, tw);
  conv_kernel   <<<8192, 256, 0, stream>>>(xp, tw, (u32*)ysb);
  mix_kernel    <<<1024, 256, 0, stream>>>(ysb, b1, w2, b2, wa, ba, wr, br, wz, bz, out);
  softmax_kernel<<<32,   256, 0, stream>>>(gumbel, out);
  tiny_kernel   <<<1,    64,  0, stream>>>(out);
}

// Round 2
// 1064.861 us; speedup vs baseline: 6.0433x; 6.0433x over previous
//
#include <hip/hip_runtime.h>
#include <hip/hip_bf16.h>

typedef unsigned int u32;
typedef unsigned short u16;

// Geometry: B=32, IC=1, N=64, KN=128, KS=65, PAD=16, R=8, LAT=32, HW=32
#define KYP 72            // kx padded 65 -> 72 per ky row (zero weights in pad)
#define KT  4680          // 65*72 flattened K
#define KPAD 4736         // padded to 74*64
#define NSTEPS 74

// d_out element offsets (fp32)
#define OUT_ATTN 0
#define OUT_QTR  262144
#define OUT_PR   524288
#define OUT_AS   524296
#define OUT_OFF  786440
#define OUT_TH   786448
#define OUT_Z    1310736

typedef __attribute__((ext_vector_type(8))) short bf16x8;
typedef __attribute__((ext_vector_type(4))) float f32x4;

__device__ const float OFFS[8] = {
  0.0f,
  0.78539816339744830961f,
  1.57079632679489661923f,
  2.35619449019234492885f,
  3.14159265358979323846f,
 -2.35619449019234492885f,
 -1.57079632679489661923f,
 -0.78539816339744830961f
};

__device__ __forceinline__ float leaky_(float v){ return v >= 0.0f ? v : 0.01f*v; }

__device__ __forceinline__ u16 f2bf(float f){
  u32 x = __float_as_uint(f);
  u32 r = (x + 0x7FFFu + ((x >> 16) & 1u)) >> 16;   // RNE
  return (u16)r;
}

__device__ __forceinline__ void gload_lds16(const void* g, void* l){
  __builtin_amdgcn_global_load_lds((const __attribute__((address_space(1))) u32*)g,
                                   (__attribute__((address_space(3))) u32*)l, 16, 0, 0);
}

// ---------------- xshift: x(32,64,64) f32 -> xsh[s=8][b=32][row=96][col=128] bf16 ----------------
// xsh[s][b][row][col] = xpad(b, row, col+s), xpad = 96x96 zero-padded (PAD=16) image.
__global__ __launch_bounds__(256) void xshift_kernel(const float* __restrict__ x, u16* __restrict__ xsh){
  int t = blockIdx.x*256 + threadIdx.x;      // 8*32*96*16 = 393216 threads, 16B each
  if (t >= 393216) return;
  int c8  = t & 15;
  int u   = t >> 4;
  int row = u % 96;
  int v   = u / 96;
  int b   = v & 31;
  int s   = v >> 5;
  int iy = row - 16;
  u16 h[8];
#pragma unroll
  for (int j = 0; j < 8; ++j){
    int ix = c8*8 + j + s - 16;
    float val = 0.0f;
    if (iy >= 0 && iy < 64 && ix >= 0 && ix < 64) val = x[(b*64 + iy)*64 + ix];
    h[j] = f2bf(val);
  }
  uint4 pk;
  pk.x = (u32)h[0] | ((u32)h[1] << 16);
  pk.y = (u32)h[2] | ((u32)h[3] << 16);
  pk.z = (u32)h[4] | ((u32)h[5] << 16);
  pk.w = (u32)h[6] | ((u32)h[7] << 16);
  ((uint4*)xsh)[t] = pk;
}

// ---------------- rotate: w1(128,65,65) -> twb[n=rot*128+kn][KPAD] bf16, ky-rows padded to 72 ----------------
__global__ __launch_bounds__(256) void rotate_kernel(const float* __restrict__ w1, u16* __restrict__ twb){
  __shared__ float wsh[4225];
  int n = blockIdx.x;          // 0..1023
  int kn = n & 127, rot = n >> 7;
  for (int i = threadIdx.x; i < 4225; i += 256) wsh[i] = w1[kn*4225 + i];
  __syncthreads();
  float th  = 0.78539816339744830961f * (float)rot;
  float cth = cosf(th), sth = sinf(th);
  for (int t = threadIdx.x; t < KPAD; t += 256){
    int ky = t / KYP, kx = t - ky*KYP;
    u16 out = 0;
    if (ky < 65 && kx < 65){
      float yy = (2.0f*(float)ky + 1.0f)/65.0f - 1.0f;
      float xx = (2.0f*(float)kx + 1.0f)/65.0f - 1.0f;
      float xs  =  cth*xx + sth*yy;
      float ysv = -sth*xx + cth*yy;
      float px = ((xs  + 1.0f)*65.0f - 1.0f)*0.5f;
      float py = ((ysv + 1.0f)*65.0f - 1.0f)*0.5f;
      float x0 = floorf(px), y0 = floorf(py);
      float wx = px - x0, wy = py - y0;
      auto samp = [&](float yf, float xf)->float{
        bool valid = (yf >= 0.0f) && (yf < 65.0f) && (xf >= 0.0f) && (xf < 65.0f);
        int yc = (int)fminf(fmaxf(yf, 0.0f), 64.0f);
        int xc = (int)fminf(fmaxf(xf, 0.0f), 64.0f);
        return valid ? wsh[yc*65 + xc] : 0.0f;
      };
      float val = samp(y0,      x0     )*(1.0f-wy)*(1.0f-wx)
                + samp(y0,      x0+1.0f)*(1.0f-wy)*wx
                + samp(y0+1.0f, x0     )*wy*(1.0f-wx)
                + samp(y0+1.0f, x0+1.0f)*wy*wx;
      out = f2bf(val);
    }
    twb[(size_t)n*KPAD + t] = out;
  }
}

// ---------------- implicit-GEMM conv: C[m=32768][n=1024] bf16 ----------------
// m = ((b>>2)*32 + ox)*128 + (b&3)*32 + oy ; n = r*128 + kn
// Block: 128 pixels (fixed ox, 4 b's x 32 oy) x 128 channels. BK=64, 74 steps.
__global__ __launch_bounds__(256) void gemm_kernel(const u16* __restrict__ xsh,
                                                   const u16* __restrict__ twb,
                                                   u16* __restrict__ ys){
  __shared__ u16 As[128*64];
  __shared__ u16 Bs[128*64];
  int bid  = blockIdx.x;
  int nblk = bid & 7, mblk = bid >> 3;
  int bg = mblk >> 5, ox = mblk & 31;
  int t = threadIdx.x;
  int lane = t & 63, w = t >> 6;
  int wr = w >> 1, wn = w & 1;

  f32x4 acc[4][4];
#pragma unroll
  for (int i = 0; i < 4; ++i)
#pragma unroll
    for (int j = 0; j < 4; ++j) acc[i][j] = (f32x4){0.f,0.f,0.f,0.f};

  const int s_   = ox & 7;
  const int colb = ox & ~7;               // ox - s_
  // per-chunk invariants
  int iArr[4], jswArr[4];
  const u16* bBase[4];
  int aBase[4];
#pragma unroll
  for (int c = 0; c < 4; ++c){
    int e0 = c*2048 + t*8;
    int i  = e0 >> 6;
    int j0 = e0 & 63;
    int jsw = j0 ^ ((i & 7) << 3);        // source pre-swizzle (T2, rule #21)
    iArr[c] = i; jswArr[c] = jsw;
    bBase[c] = twb + (size_t)(nblk*128 + i)*KPAD + jsw;
    int b_ = (bg << 2) + (i >> 5), oy = i & 31;
    aBase[c] = ((s_*32 + b_)*96 + oy)*128 + colb;   // add (ky*128 + kx0) per step
  }

  for (int step = 0; step < NSTEPS; ++step){
    int k0 = step*64;
#pragma unroll
    for (int c = 0; c < 4; ++c){
      int k  = k0 + jswArr[c];
      u32 ky = (u32)k / KYP;
      int kx0 = k - (int)ky*KYP;
      int gofs = (ky >= 65) ? 0 : (aBase[c] + (int)ky*128 + kx0);
      gload_lds16(xsh + gofs, As + c*2048 + w*512);
    }
#pragma unroll
    for (int c = 0; c < 4; ++c){
      gload_lds16(bBase[c] + k0, Bs + c*2048 + w*512);
    }
    __syncthreads();
#pragma unroll
    for (int kk = 0; kk < 64; kk += 32){
      bf16x8 a[4], bf[4];
      int kb = (kk + ((lane >> 4) << 3))*2;
#pragma unroll
      for (int mf = 0; mf < 4; ++mf){
        int row = wr*64 + mf*16 + (lane & 15);
        int off = (row*128 + kb) ^ ((row & 7) << 4);
        a[mf] = *(const bf16x8*)((const char*)As + off);
      }
#pragma unroll
      for (int nf = 0; nf < 4; ++nf){
        int row = wn*64 + nf*16 + (lane & 15);
        int off = (row*128 + kb) ^ ((row & 7) << 4);
        bf[nf] = *(const bf16x8*)((const char*)Bs + off);
      }
#pragma unroll
      for (int mf = 0; mf < 4; ++mf)
#pragma unroll
        for (int nf = 0; nf < 4; ++nf)
          acc[mf][nf] = __builtin_amdgcn_mfma_f32_16x16x32_bf16(a[mf], bf[nf], acc[mf][nf], 0, 0, 0);
    }
    __syncthreads();
  }

  int m_base = mblk*128 + wr*64;
  int n_base = nblk*128 + wn*64;
  int rsub = (lane >> 4) << 2;
  int csub = lane & 15;
#pragma unroll
  for (int mf = 0; mf < 4; ++mf)
#pragma unroll
    for (int nf = 0; nf < 4; ++nf)
#pragma unroll
      for (int j = 0; j < 4; ++j){
        int m = m_base + mf*16 + rsub + j;
        int n = n_base + nf*16 + csub;
        ys[(size_t)m*1024 + n] = f2bf(acc[mf][nf][j]);
      }
}

// ---------------- mix: per row rho=(b,r,pix): xa -> h -> {z, attn, theta} ----------------
__global__ __launch_bounds__(256) void mix_kernel(const u16* __restrict__ ys,
    const float* __restrict__ b1, const float* __restrict__ w2, const float* __restrict__ b2,
    const float* __restrict__ wa, const float* __restrict__ ba,
    const float* __restrict__ wr, const float* __restrict__ br,
    const float* __restrict__ wz, const float* __restrict__ bz,
    float* __restrict__ out){
  int rho = blockIdx.x*256 + threadIdx.x;   // (b*8+r)*1024 + pix
  int pix = rho & 1023;
  int r   = (rho >> 10) & 7;
  int b   = rho >> 13;
  int oy = pix >> 5, oxm = pix & 31;
  int m = ((b >> 2)*32 + oxm)*128 + (b & 3)*32 + oy;
  const u16* yrow = ys + (size_t)m*1024 + (size_t)r*128;
  float zacc[67];
#pragma unroll
  for (int c = 0; c < 67; ++c) zacc[c] = 0.0f;
#pragma unroll 1
  for (int half = 0; half < 2; ++half){
    float hacc[64];
#pragma unroll
    for (int o = 0; o < 64; ++o) hacc[o] = 0.0f;
#pragma unroll 1
    for (int knc = 0; knc < 128; knc += 16){
      float xv[16];
      const uint4* yp = (const uint4*)(yrow + knc);
      uint4 v0 = yp[0], v1 = yp[1];
      u32 vv[8] = {v0.x,v0.y,v0.z,v0.w,v1.x,v1.y,v1.z,v1.w};
#pragma unroll
      for (int j = 0; j < 8; ++j){
        float lo = __uint_as_float(vv[j] << 16);
        float hi = __uint_as_float(vv[j] & 0xFFFF0000u);
        xv[2*j]   = leaky_(lo + b1[knc + 2*j]);
        xv[2*j+1] = leaky_(hi + b1[knc + 2*j + 1]);
      }
#pragma unroll
      for (int o = 0; o < 64; ++o){
        const float* wrow = w2 + (half*64 + o)*128 + knc;   // uniform -> s_load
#pragma unroll
        for (int i = 0; i < 16; ++i) hacc[o] += wrow[i]*xv[i];
      }
    }
#pragma unroll
    for (int o = 0; o < 64; ++o) hacc[o] = leaky_(hacc[o] + b2[half*64 + o]);
#pragma unroll
    for (int c = 0; c < 64; ++c){
      const float* wrow = wz + c*128 + half*64;
      float s = 0.0f;
#pragma unroll
      for (int o = 0; o < 64; ++o) s += wrow[o]*hacc[o];
      zacc[c] += s;
    }
    {
      const float* wrow = wa + half*64;
      float s = 0.0f;
#pragma unroll
      for (int o = 0; o < 64; ++o) s += wrow[o]*hacc[o];
      zacc[64] += s;
    }
    {
      const float* wrow = wr + half*64;
      float s = 0.0f;
#pragma unroll
      for (int o = 0; o < 64; ++o) s += wrow[o]*hacc[o];
      zacc[65] += s;
    }
    {
      const float* wrow = wr + 128 + half*64;
      float s = 0.0f;
#pragma unroll
      for (int o = 0; o < 64; ++o) s += wrow[o]*hacc[o];
      zacc[66] += s;
    }
  }
  float* zout = out + OUT_Z + (size_t)b*524288 + (size_t)r*1024 + pix;
#pragma unroll
  for (int c = 0; c < 64; ++c) zout[(size_t)c*8192] = zacc[c] + bz[c];
  float qn = OFFS[r] / 3.14159265358979323846f;
  float pr = -0.5f*qn*qn - 1.14472988584940017414f - 0.91893853320467274178f;
  out[OUT_ATTN + rho] = zacc[64] + ba[0] + pr;
  out[OUT_TH + ((size_t)b*2 + 0)*8192 + (size_t)r*1024 + pix] = zacc[65] + br[0] + OFFS[r];
  out[OUT_TH + ((size_t)b*2 + 1)*8192 + (size_t)r*1024 + pix] = zacc[66] + br[1];
}

// ---------------- softmax: per batch b, over 8192 attn values ----------------
__global__ __launch_bounds__(256) void softmax_kernel(const float* __restrict__ gumbel, float* __restrict__ out){
  __shared__ float a[8192];
  __shared__ float red[256];
  const int b = blockIdx.x, t = threadIdx.x;
  const float* attn = out + OUT_ATTN + (size_t)b*8192;
  float m = -3.0e38f;
  for (int i = t; i < 8192; i += 256){ float v = attn[i]; a[i] = v; m = fmaxf(m, v); }
  red[t] = m; __syncthreads();
#pragma unroll
  for (int s = 128; s > 0; s >>= 1){ if (t < s) red[t] = fmaxf(red[t], red[t+s]); __syncthreads(); }
  m = red[0]; __syncthreads();
  float s1 = 0.0f;
  for (int i = t; i < 8192; i += 256) s1 += expf(a[i] - m);
  red[t] = s1; __syncthreads();
#pragma unroll
  for (int s = 128; s > 0; s >>= 1){ if (t < s) red[t] += red[t+s]; __syncthreads(); }
  float lse = m + logf(red[0]);
  __syncthreads();
  float* q = out + OUT_QTR + (size_t)b*8192;
  for (int i = t; i < 8192; i += 256) q[i] = a[i] - lse;
  const float* g = gumbel + (size_t)b*8192;
  float m2 = -3.0e38f;
  for (int i = t; i < 8192; i += 256){ float v = a[i] + g[i]; a[i] = v; m2 = fmaxf(m2, v); }
  __syncthreads();
  red[t] = m2; __syncthreads();
#pragma unroll
  for (int s = 128; s > 0; s >>= 1){ if (t < s) red[t] = fmaxf(red[t], red[t+s]); __syncthreads(); }
  m2 = red[0]; __syncthreads();
  float s2 = 0.0f;
  for (int i = t; i < 8192; i += 256) s2 += expf(a[i] - m2);
  red[t] = s2; __syncthreads();
#pragma unroll
  for (int s = 128; s > 0; s >>= 1){ if (t < s) red[t] += red[t+s]; __syncthreads(); }
  float inv = 1.0f/red[0];
  float* as_ = out + OUT_AS + (size_t)b*8192;
  for (int i = t; i < 8192; i += 256) as_[i] = expf(a[i] - m2)*inv;
}

// ---------------- tiny: p_r and offsets ----------------
__global__ void tiny_kernel(float* __restrict__ out){
  int t = threadIdx.x;
  if (t < 8){
    float off = OFFS[t];
    out[OUT_OFF + t] = off;
    float qn = off / 3.14159265358979323846f;
    out[OUT_PR + t] = -0.5f*qn*qn - 1.14472988584940017414f - 0.91893853320467274178f;
  }
}

extern "C" void kernel_launch(void* const* d_in, const int* in_sizes, int n_in,
                              void* d_out, int out_size, void* d_ws, size_t ws_size,
                              hipStream_t stream){
  const float* x      = (const float*)d_in[0];
  const float* w1     = (const float*)d_in[1];
  const float* b1     = (const float*)d_in[2];
  const float* w2     = (const float*)d_in[3];
  const float* b2     = (const float*)d_in[4];
  const float* wa     = (const float*)d_in[5];
  const float* ba     = (const float*)d_in[6];
  const float* wr     = (const float*)d_in[7];
  const float* br     = (const float*)d_in[8];
  const float* wz     = (const float*)d_in[9];
  const float* bz     = (const float*)d_in[10];
  const float* gumbel = (const float*)d_in[11];
  float* out = (float*)d_out;

  // workspace layout (bytes):
  // twb : 1024*4736*2      =  9,699,328
  // xsh : 8*32*96*128*2    =  6,291,456
  // ys  : 32768*1024*2     = 67,108,864   (total ~83.1 MB)
  u16* twb = (u16*)d_ws;
  u16* xsh = twb + (size_t)1024*KPAD;
  u16* ys  = xsh + (size_t)8*32*96*128;

  xshift_kernel <<<1536, 256, 0, stream>>>(x, xsh);
  rotate_kernel <<<1024, 256, 0, stream>>>(w1, twb);
  gemm_kernel   <<<2048, 256, 0, stream>>>(xsh, twb, ys);
  mix_kernel    <<<1024, 256, 0, stream>>>(ys, b1, w2, b2, wa, ba, wr, br, wz, bz, out);
  softmax_kernel<<<32,   256, 0, stream>>>(gumbel, out);
  tiny_kernel   <<<1,    64,  0, stream>>>(out);
}

// Round 3
// 416.132 us; speedup vs baseline: 15.4645x; 2.5590x over previous
//
#include <hip/hip_runtime.h>
#include <hip/hip_bf16.h>

typedef unsigned int u32;
typedef unsigned short u16;

// Geometry: B=32, IC=1, N=64, KN=128, KS=65, PAD=16, R=8, LAT=32, HW=32
#define KYP 72            // kx padded 65 -> 72 per ky row (zero weights in pad)
#define KT  4680          // 65*72 flattened K
#define KPAD 4736         // padded to 74*64
#define NSTEPS 74

// d_out element offsets (fp32)
#define OUT_ATTN 0
#define OUT_QTR  262144
#define OUT_PR   524288
#define OUT_AS   524296
#define OUT_OFF  786440
#define OUT_TH   786448
#define OUT_Z    1310736

typedef __attribute__((ext_vector_type(8))) short bf16x8;
typedef __attribute__((ext_vector_type(4))) float f32x4;

__device__ const float OFFS[8] = {
  0.0f,
  0.78539816339744830961f,
  1.57079632679489661923f,
  2.35619449019234492885f,
  3.14159265358979323846f,
 -2.35619449019234492885f,
 -1.57079632679489661923f,
 -0.78539816339744830961f
};

__device__ __forceinline__ float leaky_(float v){ return v >= 0.0f ? v : 0.01f*v; }

__device__ __forceinline__ u16 f2bf(float f){
  u32 x = __float_as_uint(f);
  u32 r = (x + 0x7FFFu + ((x >> 16) & 1u)) >> 16;   // RNE
  return (u16)r;
}

__device__ __forceinline__ void gload_lds16(const void* g, void* l){
  __builtin_amdgcn_global_load_lds((const __attribute__((address_space(1))) u32*)g,
                                   (__attribute__((address_space(3))) u32*)l, 16, 0, 0);
}

// ---------------- xshift: x(32,64,64) f32 -> xsh[s=8][b=32][row=96][col=128] bf16 ----------------
__global__ __launch_bounds__(256) void xshift_kernel(const float* __restrict__ x, u16* __restrict__ xsh){
  int t = blockIdx.x*256 + threadIdx.x;      // 8*32*96*16 = 393216 threads, 16B each
  if (t >= 393216) return;
  int c8  = t & 15;
  int u   = t >> 4;
  int row = u % 96;
  int v   = u / 96;
  int b   = v & 31;
  int s   = v >> 5;
  int iy = row - 16;
  u16 h[8];
#pragma unroll
  for (int j = 0; j < 8; ++j){
    int ix = c8*8 + j + s - 16;
    float val = 0.0f;
    if (iy >= 0 && iy < 64 && ix >= 0 && ix < 64) val = x[(b*64 + iy)*64 + ix];
    h[j] = f2bf(val);
  }
  uint4 pk;
  pk.x = (u32)h[0] | ((u32)h[1] << 16);
  pk.y = (u32)h[2] | ((u32)h[3] << 16);
  pk.z = (u32)h[4] | ((u32)h[5] << 16);
  pk.w = (u32)h[6] | ((u32)h[7] << 16);
  ((uint4*)xsh)[t] = pk;
}

// ---------------- rotate: w1(128,65,65) -> twb[n=rot*128+kn][KPAD] bf16 ----------------
__global__ __launch_bounds__(256) void rotate_kernel(const float* __restrict__ w1, u16* __restrict__ twb){
  __shared__ float wsh[4225];
  int n = blockIdx.x;          // 0..1023
  int kn = n & 127, rot = n >> 7;
  for (int i = threadIdx.x; i < 4225; i += 256) wsh[i] = w1[kn*4225 + i];
  __syncthreads();
  float th  = 0.78539816339744830961f * (float)rot;
  float cth = cosf(th), sth = sinf(th);
  for (int t = threadIdx.x; t < KPAD; t += 256){
    int ky = t / KYP, kx = t - ky*KYP;
    u16 out = 0;
    if (ky < 65 && kx < 65){
      float yy = (2.0f*(float)ky + 1.0f)/65.0f - 1.0f;
      float xx = (2.0f*(float)kx + 1.0f)/65.0f - 1.0f;
      float xs  =  cth*xx + sth*yy;
      float ysv = -sth*xx + cth*yy;
      float px = ((xs  + 1.0f)*65.0f - 1.0f)*0.5f;
      float py = ((ysv + 1.0f)*65.0f - 1.0f)*0.5f;
      float x0 = floorf(px), y0 = floorf(py);
      float wx = px - x0, wy = py - y0;
      auto samp = [&](float yf, float xf)->float{
        bool valid = (yf >= 0.0f) && (yf < 65.0f) && (xf >= 0.0f) && (xf < 65.0f);
        int yc = (int)fminf(fmaxf(yf, 0.0f), 64.0f);
        int xc = (int)fminf(fmaxf(xf, 0.0f), 64.0f);
        return valid ? wsh[yc*65 + xc] : 0.0f;
      };
      float val = samp(y0,      x0     )*(1.0f-wy)*(1.0f-wx)
                + samp(y0,      x0+1.0f)*(1.0f-wy)*wx
                + samp(y0+1.0f, x0     )*wy*(1.0f-wx)
                + samp(y0+1.0f, x0+1.0f)*wy*wx;
      out = f2bf(val);
    }
    twb[(size_t)n*KPAD + t] = out;
  }
}

// ---------------- implicit-GEMM conv: C[m=32768][n=1024] bf16 (unchanged from R2) ----------------
__global__ __launch_bounds__(256) void gemm_kernel(const u16* __restrict__ xsh,
                                                   const u16* __restrict__ twb,
                                                   u16* __restrict__ ys){
  __shared__ u16 As[128*64];
  __shared__ u16 Bs[128*64];
  int bid  = blockIdx.x;
  int nblk = bid & 7, mblk = bid >> 3;
  int bg = mblk >> 5, ox = mblk & 31;
  int t = threadIdx.x;
  int lane = t & 63, w = t >> 6;
  int wr = w >> 1, wn = w & 1;

  f32x4 acc[4][4];
#pragma unroll
  for (int i = 0; i < 4; ++i)
#pragma unroll
    for (int j = 0; j < 4; ++j) acc[i][j] = (f32x4){0.f,0.f,0.f,0.f};

  const int s_   = ox & 7;
  const int colb = ox & ~7;
  int iArr[4], jswArr[4];
  const u16* bBase[4];
  int aBase[4];
#pragma unroll
  for (int c = 0; c < 4; ++c){
    int e0 = c*2048 + t*8;
    int i  = e0 >> 6;
    int j0 = e0 & 63;
    int jsw = j0 ^ ((i & 7) << 3);
    iArr[c] = i; jswArr[c] = jsw;
    bBase[c] = twb + (size_t)(nblk*128 + i)*KPAD + jsw;
    int b_ = (bg << 2) + (i >> 5), oy = i & 31;
    aBase[c] = ((s_*32 + b_)*96 + oy)*128 + colb;
  }

  for (int step = 0; step < NSTEPS; ++step){
    int k0 = step*64;
#pragma unroll
    for (int c = 0; c < 4; ++c){
      int k  = k0 + jswArr[c];
      u32 ky = (u32)k / KYP;
      int kx0 = k - (int)ky*KYP;
      int gofs = (ky >= 65) ? 0 : (aBase[c] + (int)ky*128 + kx0);
      gload_lds16(xsh + gofs, As + c*2048 + w*512);
    }
#pragma unroll
    for (int c = 0; c < 4; ++c){
      gload_lds16(bBase[c] + k0, Bs + c*2048 + w*512);
    }
    __syncthreads();
#pragma unroll
    for (int kk = 0; kk < 64; kk += 32){
      bf16x8 a[4], bf[4];
      int kb = (kk + ((lane >> 4) << 3))*2;
#pragma unroll
      for (int mf = 0; mf < 4; ++mf){
        int row = wr*64 + mf*16 + (lane & 15);
        int off = (row*128 + kb) ^ ((row & 7) << 4);
        a[mf] = *(const bf16x8*)((const char*)As + off);
      }
#pragma unroll
      for (int nf = 0; nf < 4; ++nf){
        int row = wn*64 + nf*16 + (lane & 15);
        int off = (row*128 + kb) ^ ((row & 7) << 4);
        bf[nf] = *(const bf16x8*)((const char*)Bs + off);
      }
#pragma unroll
      for (int mf = 0; mf < 4; ++mf)
#pragma unroll
        for (int nf = 0; nf < 4; ++nf)
          acc[mf][nf] = __builtin_amdgcn_mfma_f32_16x16x32_bf16(a[mf], bf[nf], acc[mf][nf], 0, 0, 0);
    }
    __syncthreads();
  }

  int m_base = mblk*128 + wr*64;
  int n_base = nblk*128 + wn*64;
  int rsub = (lane >> 4) << 2;
  int csub = lane & 15;
#pragma unroll
  for (int mf = 0; mf < 4; ++mf)
#pragma unroll
    for (int nf = 0; nf < 4; ++nf)
#pragma unroll
      for (int j = 0; j < 4; ++j){
        int m = m_base + mf*16 + rsub + j;
        int n = n_base + nf*16 + csub;
        ys[(size_t)m*1024 + n] = f2bf(acc[mf][nf][j]);
      }
}

// ---------------- mix (MFMA): block = (b, oy); 32 ys rows x 8 r = 256 rho rows ----------------
// GEMM1: xa[256x128] @ w2^T -> h ; GEMM2: h[256x128] @ Wcat^T[80x128] -> z/attn/theta
__global__ __launch_bounds__(512) void mix_kernel(const u16* __restrict__ ys,
    const float* __restrict__ b1, const float* __restrict__ w2, const float* __restrict__ b2,
    const float* __restrict__ wa, const float* __restrict__ ba,
    const float* __restrict__ wr, const float* __restrict__ br,
    const float* __restrict__ wz, const float* __restrict__ bz,
    float* __restrict__ out){
  __shared__ __align__(16) u16 Ah[256*128];    // 64 KB: xa then h (both swizzled)
  __shared__ __align__(16) u16 W2s[128*128];   // 32 KB
  __shared__ __align__(16) u16 Wcs[80*128];    // 20 KB
  __shared__ float b2s[128];
  __shared__ float bcs[80];

  const int blk = blockIdx.x;
  const int b   = blk >> 5, oy = blk & 31;
  const int t    = threadIdx.x;
  const int lane = t & 63;
  const int w    = t >> 6;              // wave = rotation r

  // ---- stage xa = leaky(ys + b1) -> Ah (swizzled bf16) ----
  {
    const int kn0 = (t & 15)*8;
    const int r_  = (t >> 4) & 7;
    float b1v[8];
#pragma unroll
    for (int j = 0; j < 8; ++j) b1v[j] = b1[kn0 + j];
#pragma unroll
    for (int i = 0; i < 8; ++i){
      int m_loc = 4*i + (t >> 7);       // 0..31 == ox
      int row_m = (((b >> 2)*32 + m_loc)*128) + (b & 3)*32 + oy;   // gemm m-mapping
      uint4 v = *(const uint4*)(ys + (size_t)row_m*1024 + r_*128 + kn0);
      u32 vv[4] = {v.x, v.y, v.z, v.w};
      u16 hh[8];
#pragma unroll
      for (int j = 0; j < 4; ++j){
        float lo = __uint_as_float(vv[j] << 16);
        float hi = __uint_as_float(vv[j] & 0xFFFF0000u);
        hh[2*j]   = f2bf(leaky_(lo + b1v[2*j]));
        hh[2*j+1] = f2bf(leaky_(hi + b1v[2*j+1]));
      }
      int Arow = r_*32 + m_loc;
      int off = (Arow*256 + kn0*2) ^ ((Arow & 7) << 4);
      uint4 pk;
      pk.x = (u32)hh[0] | ((u32)hh[1] << 16);
      pk.y = (u32)hh[2] | ((u32)hh[3] << 16);
      pk.z = (u32)hh[4] | ((u32)hh[5] << 16);
      pk.w = (u32)hh[6] | ((u32)hh[7] << 16);
      *(uint4*)((char*)Ah + off) = pk;
    }
  }
  // ---- stage w2 -> W2s ----
#pragma unroll
  for (int i = 0; i < 4; ++i){
    int ch = i*512 + t;                 // 2048 chunks
    int row = ch >> 4, kn0 = (ch & 15)*8;
    const float* src = w2 + row*128 + kn0;
    u16 hh[8];
#pragma unroll
    for (int j = 0; j < 8; ++j) hh[j] = f2bf(src[j]);
    int off = (row*256 + kn0*2) ^ ((row & 7) << 4);
    uint4 pk;
    pk.x = (u32)hh[0] | ((u32)hh[1] << 16);
    pk.y = (u32)hh[2] | ((u32)hh[3] << 16);
    pk.z = (u32)hh[4] | ((u32)hh[5] << 16);
    pk.w = (u32)hh[6] | ((u32)hh[7] << 16);
    *(uint4*)((char*)W2s + off) = pk;
  }
  // ---- stage Wcat -> Wcs : rows 0..63 wz, 64 wa, 65/66 wr, 67..79 zero ----
#pragma unroll
  for (int i = 0; i < 3; ++i){
    int ch = i*512 + t;                 // 1280 chunks
    if (ch < 1280){
      int row = ch >> 4, kn0 = (ch & 15)*8;
      const float* src = nullptr;
      if (row < 64)      src = wz + row*128 + kn0;
      else if (row == 64) src = wa + kn0;
      else if (row == 65) src = wr + kn0;
      else if (row == 66) src = wr + 128 + kn0;
      u16 hh[8];
#pragma unroll
      for (int j = 0; j < 8; ++j) hh[j] = src ? f2bf(src[j]) : (u16)0;
      int off = (row*256 + kn0*2) ^ ((row & 7) << 4);
      uint4 pk;
      pk.x = (u32)hh[0] | ((u32)hh[1] << 16);
      pk.y = (u32)hh[2] | ((u32)hh[3] << 16);
      pk.z = (u32)hh[4] | ((u32)hh[5] << 16);
      pk.w = (u32)hh[6] | ((u32)hh[7] << 16);
      *(uint4*)((char*)Wcs + off) = pk;
    }
  }
  if (t < 128) b2s[t] = b2[t];
  if (t < 80){
    float v = 0.0f;
    if (t < 64) v = bz[t];
    else if (t == 64) v = ba[0];
    else if (t == 65) v = br[0];
    else if (t == 66) v = br[1];
    bcs[t] = v;
  }
  __syncthreads();

  // ---- GEMM1: h_pre = xa @ w2^T, wave w handles rows w*32..w*32+31 ----
  f32x4 acc1[2][8];
#pragma unroll
  for (int mf = 0; mf < 2; ++mf)
#pragma unroll
    for (int nf = 0; nf < 8; ++nf) acc1[mf][nf] = (f32x4){0.f,0.f,0.f,0.f};
#pragma unroll
  for (int kk = 0; kk < 128; kk += 32){
    int kb = (kk + ((lane >> 4) << 3))*2;
    bf16x8 a[2], bv[8];
#pragma unroll
    for (int mf = 0; mf < 2; ++mf){
      int row = w*32 + mf*16 + (lane & 15);
      int off = (row*256 + kb) ^ ((row & 7) << 4);
      a[mf] = *(const bf16x8*)((const char*)Ah + off);
    }
#pragma unroll
    for (int nf = 0; nf < 8; ++nf){
      int row = nf*16 + (lane & 15);
      int off = (row*256 + kb) ^ ((row & 7) << 4);
      bv[nf] = *(const bf16x8*)((const char*)W2s + off);
    }
#pragma unroll
    for (int mf = 0; mf < 2; ++mf)
#pragma unroll
      for (int nf = 0; nf < 8; ++nf)
        acc1[mf][nf] = __builtin_amdgcn_mfma_f32_16x16x32_bf16(a[mf], bv[nf], acc1[mf][nf], 0, 0, 0);
  }
  __syncthreads();   // all waves done reading Ah

  // ---- h = leaky(h_pre + b2) -> overwrite Ah (bf16, swizzled) ----
#pragma unroll
  for (int mf = 0; mf < 2; ++mf)
#pragma unroll
    for (int nf = 0; nf < 8; ++nf){
      int col = nf*16 + (lane & 15);
      float bb = b2s[col];
#pragma unroll
      for (int j = 0; j < 4; ++j){
        int row = w*32 + mf*16 + ((lane >> 4) << 2) + j;
        u16 hv = f2bf(leaky_(acc1[mf][nf][j] + bb));
        int off = (row*256 + col*2) ^ ((row & 7) << 4);
        *(u16*)((char*)Ah + off) = hv;
      }
    }
  __syncthreads();

  // ---- GEMM2: outs = h @ Wcat^T ----
  f32x4 acc2[2][5];
#pragma unroll
  for (int mf = 0; mf < 2; ++mf)
#pragma unroll
    for (int nf = 0; nf < 5; ++nf) acc2[mf][nf] = (f32x4){0.f,0.f,0.f,0.f};
#pragma unroll
  for (int kk = 0; kk < 128; kk += 32){
    int kb = (kk + ((lane >> 4) << 3))*2;
    bf16x8 a[2], bv[5];
#pragma unroll
    for (int mf = 0; mf < 2; ++mf){
      int row = w*32 + mf*16 + (lane & 15);
      int off = (row*256 + kb) ^ ((row & 7) << 4);
      a[mf] = *(const bf16x8*)((const char*)Ah + off);
    }
#pragma unroll
    for (int nf = 0; nf < 5; ++nf){
      int row = nf*16 + (lane & 15);
      int off = (row*256 + kb) ^ ((row & 7) << 4);
      bv[nf] = *(const bf16x8*)((const char*)Wcs + off);
    }
#pragma unroll
    for (int mf = 0; mf < 2; ++mf)
#pragma unroll
      for (int nf = 0; nf < 5; ++nf)
        acc2[mf][nf] = __builtin_amdgcn_mfma_f32_16x16x32_bf16(a[mf], bv[nf], acc2[mf][nf], 0, 0, 0);
  }

  // ---- epilogue: fused bias / p_r / offsets, direct stores ----
  const int r = w;
  float off_r = OFFS[r];
  float qn = off_r / 3.14159265358979323846f;
  float pr = -0.5f*qn*qn - 1.14472988584940017414f - 0.91893853320467274178f;
  const int pixb = oy*32;
#pragma unroll
  for (int mf = 0; mf < 2; ++mf)
#pragma unroll
    for (int nf = 0; nf < 5; ++nf){
      int c = nf*16 + (lane & 15);
#pragma unroll
      for (int j = 0; j < 4; ++j){
        int ox = mf*16 + ((lane >> 4) << 2) + j;
        float val = acc2[mf][nf][j];
        if (c < 64){
          out[OUT_Z + (size_t)b*524288 + (size_t)c*8192 + r*1024 + pixb + ox] = val + bcs[c];
        } else if (c == 64){
          out[OUT_ATTN + (size_t)(b*8 + r)*1024 + pixb + ox] = val + bcs[64] + pr;
        } else if (c == 65){
          out[OUT_TH + ((size_t)b*2)*8192 + r*1024 + pixb + ox] = val + bcs[65] + off_r;
        } else if (c == 66){
          out[OUT_TH + ((size_t)b*2 + 1)*8192 + r*1024 + pixb + ox] = val + bcs[66];
        }
      }
    }
}

// ---------------- softmax: per batch b, over 8192 attn values ----------------
__global__ __launch_bounds__(256) void softmax_kernel(const float* __restrict__ gumbel, float* __restrict__ out){
  __shared__ float a[8192];
  __shared__ float red[256];
  const int b = blockIdx.x, t = threadIdx.x;
  const float* attn = out + OUT_ATTN + (size_t)b*8192;
  float m = -3.0e38f;
  for (int i = t; i < 8192; i += 256){ float v = attn[i]; a[i] = v; m = fmaxf(m, v); }
  red[t] = m; __syncthreads();
#pragma unroll
  for (int s = 128; s > 0; s >>= 1){ if (t < s) red[t] = fmaxf(red[t], red[t+s]); __syncthreads(); }
  m = red[0]; __syncthreads();
  float s1 = 0.0f;
  for (int i = t; i < 8192; i += 256) s1 += expf(a[i] - m);
  red[t] = s1; __syncthreads();
#pragma unroll
  for (int s = 128; s > 0; s >>= 1){ if (t < s) red[t] += red[t+s]; __syncthreads(); }
  float lse = m + logf(red[0]);
  __syncthreads();
  float* q = out + OUT_QTR + (size_t)b*8192;
  for (int i = t; i < 8192; i += 256) q[i] = a[i] - lse;
  const float* g = gumbel + (size_t)b*8192;
  float m2 = -3.0e38f;
  for (int i = t; i < 8192; i += 256){ float v = a[i] + g[i]; a[i] = v; m2 = fmaxf(m2, v); }
  __syncthreads();
  red[t] = m2; __syncthreads();
#pragma unroll
  for (int s = 128; s > 0; s >>= 1){ if (t < s) red[t] = fmaxf(red[t], red[t+s]); __syncthreads(); }
  m2 = red[0]; __syncthreads();
  float s2 = 0.0f;
  for (int i = t; i < 8192; i += 256) s2 += expf(a[i] - m2);
  red[t] = s2; __syncthreads();
#pragma unroll
  for (int s = 128; s > 0; s >>= 1){ if (t < s) red[t] += red[t+s]; __syncthreads(); }
  float inv = 1.0f/red[0];
  float* as_ = out + OUT_AS + (size_t)b*8192;
  for (int i = t; i < 8192; i += 256) as_[i] = expf(a[i] - m2)*inv;
}

// ---------------- tiny: p_r and offsets ----------------
__global__ void tiny_kernel(float* __restrict__ out){
  int t = threadIdx.x;
  if (t < 8){
    float off = OFFS[t];
    out[OUT_OFF + t] = off;
    float qn = off / 3.14159265358979323846f;
    out[OUT_PR + t] = -0.5f*qn*qn - 1.14472988584940017414f - 0.91893853320467274178f;
  }
}

extern "C" void kernel_launch(void* const* d_in, const int* in_sizes, int n_in,
                              void* d_out, int out_size, void* d_ws, size_t ws_size,
                              hipStream_t stream){
  const float* x      = (const float*)d_in[0];
  const float* w1     = (const float*)d_in[1];
  const float* b1     = (const float*)d_in[2];
  const float* w2     = (const float*)d_in[3];
  const float* b2     = (const float*)d_in[4];
  const float* wa     = (const float*)d_in[5];
  const float* ba     = (const float*)d_in[6];
  const float* wr     = (const float*)d_in[7];
  const float* br     = (const float*)d_in[8];
  const float* wz     = (const float*)d_in[9];
  const float* bz     = (const float*)d_in[10];
  const float* gumbel = (const float*)d_in[11];
  float* out = (float*)d_out;

  // workspace layout (bytes):
  // twb : 1024*4736*2      =  9,699,328
  // xsh : 8*32*96*128*2    =  6,291,456
  // ys  : 32768*1024*2     = 67,108,864
  u16* twb = (u16*)d_ws;
  u16* xsh = twb + (size_t)1024*KPAD;
  u16* ys  = xsh + (size_t)8*32*96*128;

  xshift_kernel <<<1536, 256, 0, stream>>>(x, xsh);
  rotate_kernel <<<1024, 256, 0, stream>>>(w1, twb);
  gemm_kernel   <<<2048, 256, 0, stream>>>(xsh, twb, ys);
  mix_kernel    <<<1024, 512, 0, stream>>>(ys, b1, w2, b2, wa, ba, wr, br, wz, bz, out);
  softmax_kernel<<<32,   256, 0, stream>>>(gumbel, out);
  tiny_kernel   <<<1,    64,  0, stream>>>(out);
}

// Round 4
// 383.602 us; speedup vs baseline: 16.7759x; 1.0848x over previous
//
#include <hip/hip_runtime.h>
#include <hip/hip_bf16.h>

typedef unsigned int u32;
typedef unsigned short u16;

// Geometry: B=32, IC=1, N=64, KN=128, KS=65, PAD=16, R=8, LAT=32, HW=32
#define KYP 72            // kx padded 65 -> 72 per ky row (zero weights in pad)
#define KPAD 4736         // padded to 74*64
#define NK   74           // K-tiles of 64

// d_out element offsets (fp32)
#define OUT_ATTN 0
#define OUT_QTR  262144
#define OUT_PR   524288
#define OUT_AS   524296
#define OUT_OFF  786440
#define OUT_TH   786448
#define OUT_Z    1310736

typedef __attribute__((ext_vector_type(8))) short bf16x8;
typedef __attribute__((ext_vector_type(4))) float f32x4;

__device__ const float OFFS[8] = {
  0.0f,
  0.78539816339744830961f,
  1.57079632679489661923f,
  2.35619449019234492885f,
  3.14159265358979323846f,
 -2.35619449019234492885f,
 -1.57079632679489661923f,
 -0.78539816339744830961f
};

__device__ __forceinline__ float leaky_(float v){ return v >= 0.0f ? v : 0.01f*v; }

__device__ __forceinline__ u16 f2bf(float f){
  u32 x = __float_as_uint(f);
  u32 r = (x + 0x7FFFu + ((x >> 16) & 1u)) >> 16;   // RNE
  return (u16)r;
}

__device__ __forceinline__ void gload_lds16(const void* g, void* l){
  __builtin_amdgcn_global_load_lds((const __attribute__((address_space(1))) u32*)g,
                                   (__attribute__((address_space(3))) u32*)l, 16, 0, 0);
}

#define BARRIER() { asm volatile("" ::: "memory"); __builtin_amdgcn_s_barrier(); asm volatile("" ::: "memory"); }
#define WAITV(N)  asm volatile("s_waitcnt vmcnt(" #N ")" ::: "memory")

// ---------------- xshift: x(32,64,64) f32 -> xsh[s=8][b=32][row=96][col=128] bf16 ----------------
__global__ __launch_bounds__(256) void xshift_kernel(const float* __restrict__ x, u16* __restrict__ xsh){
  int t = blockIdx.x*256 + threadIdx.x;      // 8*32*96*16 = 393216 threads, 16B each
  if (t >= 393216) return;
  int c8  = t & 15;
  int u   = t >> 4;
  int row = u % 96;
  int v   = u / 96;
  int b   = v & 31;
  int s   = v >> 5;
  int iy = row - 16;
  u16 h[8];
#pragma unroll
  for (int j = 0; j < 8; ++j){
    int ix = c8*8 + j + s - 16;
    float val = 0.0f;
    if (iy >= 0 && iy < 64 && ix >= 0 && ix < 64) val = x[(b*64 + iy)*64 + ix];
    h[j] = f2bf(val);
  }
  uint4 pk;
  pk.x = (u32)h[0] | ((u32)h[1] << 16);
  pk.y = (u32)h[2] | ((u32)h[3] << 16);
  pk.z = (u32)h[4] | ((u32)h[5] << 16);
  pk.w = (u32)h[6] | ((u32)h[7] << 16);
  ((uint4*)xsh)[t] = pk;
}

// ---------------- rotate: w1(128,65,65) -> twb[n=rot*128+kn][KPAD] bf16 ----------------
__global__ __launch_bounds__(256) void rotate_kernel(const float* __restrict__ w1, u16* __restrict__ twb){
  __shared__ float wsh[4225];
  int n = blockIdx.x;          // 0..1023
  int kn = n & 127, rot = n >> 7;
  for (int i = threadIdx.x; i < 4225; i += 256) wsh[i] = w1[kn*4225 + i];
  __syncthreads();
  float th  = 0.78539816339744830961f * (float)rot;
  float cth = cosf(th), sth = sinf(th);
  for (int t = threadIdx.x; t < KPAD; t += 256){
    int ky = t / KYP, kx = t - ky*KYP;
    u16 out = 0;
    if (ky < 65 && kx < 65){
      float yy = (2.0f*(float)ky + 1.0f)/65.0f - 1.0f;
      float xx = (2.0f*(float)kx + 1.0f)/65.0f - 1.0f;
      float xs  =  cth*xx + sth*yy;
      float ysv = -sth*xx + cth*yy;
      float px = ((xs  + 1.0f)*65.0f - 1.0f)*0.5f;
      float py = ((ysv + 1.0f)*65.0f - 1.0f)*0.5f;
      float x0 = floorf(px), y0 = floorf(py);
      float wx = px - x0, wy = py - y0;
      auto samp = [&](float yf, float xf)->float{
        bool valid = (yf >= 0.0f) && (yf < 65.0f) && (xf >= 0.0f) && (xf < 65.0f);
        int yc = (int)fminf(fmaxf(yf, 0.0f), 64.0f);
        int xc = (int)fminf(fmaxf(xf, 0.0f), 64.0f);
        return valid ? wsh[yc*65 + xc] : 0.0f;
      };
      float val = samp(y0,      x0     )*(1.0f-wy)*(1.0f-wx)
                + samp(y0,      x0+1.0f)*(1.0f-wy)*wx
                + samp(y0+1.0f, x0     )*wy*(1.0f-wx)
                + samp(y0+1.0f, x0+1.0f)*wy*wx;
      out = f2bf(val);
    }
    twb[(size_t)n*KPAD + t] = out;
  }
}

// ---------------- implicit-GEMM conv, 256^2 8-phase: C[m=32768][n=1024] bf16 ----------------
// m = mblk*256 + lm  (lm: ox pair-major, see aOff);  n = nblk*256 + ln
// 512 threads = 8 waves (2M x 4N), BK=64, double-buffered LDS, counted vmcnt.
__global__ __launch_bounds__(512, 2) void gemm_kernel(const u16* __restrict__ xsh,
                                                      const u16* __restrict__ twb,
                                                      u16* __restrict__ ys){
  __shared__ u16 AsB[2*16384];   // [buf][256 rows][64 k] swizzled, 64 KB
  __shared__ u16 BsB[2*16384];   // 64 KB

  const int bid  = blockIdx.x;
  const int nblk = bid & 3, mblk = bid >> 2;
  const int t    = threadIdx.x;
  const int lane = t & 63, w = t >> 6;
  const int wr   = w >> 2, wn = w & 3;        // wave tile: rows wr*128, cols wn*64
  const int hi8  = (lane >> 4) << 3;

  // ---- staging thread mapping (per 8KB call c: rows c*64 + sr, cols j0e..j0e+7) ----
  const int sr  = t >> 3;
  const int j0e = (t & 7) * 8;
  const int jsw = j0e ^ ((sr & 7) << 3);      // source pre-swizzle (T2, both-sides)
  const int bg  = mblk >> 4;
  const int ox2 = (mblk & 15) * 2;
  int aOff[4];
#pragma unroll
  for (int c = 0; c < 4; ++c){
    int i  = c*64 + sr;                       // local m row
    int ox = ox2 + (i >> 7);
    int s_ = ox & 7, colb = ox & ~7;
    int b_ = (bg << 2) + ((i & 127) >> 5);
    int oy = i & 31;
    aOff[c] = ((s_*32 + b_)*96 + oy)*128 + colb;
  }
  const u16* bPtr[4];
#pragma unroll
  for (int c = 0; c < 4; ++c){
    int nloc = c*64 + sr;
    bPtr[c] = twb + (size_t)(nblk*256 + nloc)*KPAD + jsw;
  }

  auto stageA = [&](int kt, int qr){
    int k = kt*64 + jsw;
    u32 ky = (u32)k / (u32)KYP;
    int kx0 = k - (int)ky*KYP;
    bool pad = (ky >= 65);
#pragma unroll
    for (int ci = 0; ci < 2; ++ci){
      int c = qr*2 + ci;
      int gofs = pad ? 0 : (aOff[c] + (int)ky*128 + kx0);
      gload_lds16(xsh + gofs, &AsB[(kt & 1)*16384 + c*4096 + w*512]);
    }
  };
  auto stageB = [&](int kt, int qr){
#pragma unroll
    for (int ci = 0; ci < 2; ++ci){
      int c = qr*2 + ci;
      gload_lds16(bPtr[c] + kt*64, &BsB[(kt & 1)*16384 + c*4096 + w*512]);
    }
  };

  f32x4 acc[8][4];
#pragma unroll
  for (int i = 0; i < 8; ++i)
#pragma unroll
    for (int j = 0; j < 4; ++j) acc[i][j] = (f32x4){0.f,0.f,0.f,0.f};
  bf16x8 amat[4][2], bmat[4][2];

  auto readA = [&](int mh, const char* Ab){
#pragma unroll
    for (int mj = 0; mj < 4; ++mj){
      int row = wr*128 + mh*64 + mj*16 + (lane & 15);
#pragma unroll
      for (int kk = 0; kk < 2; ++kk){
        int off = (row*128 + (kk*32 + hi8)*2) ^ ((row & 7) << 4);
        amat[mj][kk] = *(const bf16x8*)(Ab + off);
      }
    }
  };
  auto readB = [&](int nh, const char* Bb){
#pragma unroll
    for (int jn = 0; jn < 2; ++jn){
      int row = wn*64 + (nh*2 + jn)*16 + (lane & 15);
#pragma unroll
      for (int kk = 0; kk < 2; ++kk){
        int off = (row*128 + (kk*32 + hi8)*2) ^ ((row & 7) << 4);
        bmat[nh*2 + jn][kk] = *(const bf16x8*)(Bb + off);
      }
    }
  };
  auto mfma16 = [&](int MH, int NH){
    __builtin_amdgcn_s_setprio(1);
#pragma unroll
    for (int mj = 0; mj < 4; ++mj)
#pragma unroll
      for (int jn = 0; jn < 2; ++jn)
#pragma unroll
        for (int kk = 0; kk < 2; ++kk)
          acc[MH*4+mj][NH*2+jn] = __builtin_amdgcn_mfma_f32_16x16x32_bf16(
              amat[mj][kk], bmat[NH*2+jn][kk], acc[MH*4+mj][NH*2+jn], 0, 0, 0);
    __builtin_amdgcn_s_setprio(0);
  };

  // ---- prologue: stage K-tile 0 (buffer 0) ----
  stageA(0, 0); stageA(0, 1); stageB(0, 0); stageB(0, 1);

  const char* Ab0 = (const char*)AsB;
  const char* Bb0 = (const char*)BsB;
  const char* Ab1 = (const char*)AsB + 32768;
  const char* Bb1 = (const char*)BsB + 32768;

  for (int kc2 = 0; kc2 < NK; kc2 += 2){
    // ======== K-tile kc2 (buffer 0) : phases 1-4, stage kt=kc2+1 -> buffer 1 ========
    stageA(kc2+1, 0);
    WAITV(2);
    BARRIER();
    readA(0, Ab0); readB(0, Bb0);
    mfma16(0, 0);
    BARRIER();
    stageA(kc2+1, 1);
    readB(1, Bb0);
    mfma16(0, 1);
    BARRIER();
    stageB(kc2+1, 0);
    readA(1, Ab0);
    mfma16(1, 1);
    BARRIER();
    stageB(kc2+1, 1);
    mfma16(1, 0);
    BARRIER();
    // ======== K-tile kc2+1 (buffer 1) : phases 5-8, stage kt=kc2+2 -> buffer 0 ========
    const bool more = (kc2 + 2) < NK;
    if (more){ stageA(kc2+2, 0); WAITV(2); }
    else     { WAITV(0); }
    BARRIER();
    readA(0, Ab1); readB(0, Bb1);
    mfma16(0, 0);
    BARRIER();
    if (more) stageA(kc2+2, 1);
    readB(1, Bb1);
    mfma16(0, 1);
    BARRIER();
    if (more) stageB(kc2+2, 0);
    readA(1, Ab1);
    mfma16(1, 1);
    BARRIER();
    if (more) stageB(kc2+2, 1);
    mfma16(1, 0);
    BARRIER();
  }

  // ---- epilogue: C store ----
  const int m_base = mblk*256 + wr*128;
  const int n_base = nblk*256 + wn*64;
  const int rsub = (lane >> 4) << 2;
  const int csub = lane & 15;
#pragma unroll
  for (int mf = 0; mf < 8; ++mf)
#pragma unroll
    for (int nf = 0; nf < 4; ++nf)
#pragma unroll
      for (int j = 0; j < 4; ++j){
        int m = m_base + mf*16 + rsub + j;
        int n = n_base + nf*16 + csub;
        ys[(size_t)m*1024 + n] = f2bf(acc[mf][nf][j]);
      }
}

// ---------------- mix (MFMA): block = (b, oy); 32 ys rows x 8 r = 256 rho rows ----------------
__global__ __launch_bounds__(512) void mix_kernel(const u16* __restrict__ ys,
    const float* __restrict__ b1, const float* __restrict__ w2, const float* __restrict__ b2,
    const float* __restrict__ wa, const float* __restrict__ ba,
    const float* __restrict__ wr, const float* __restrict__ br,
    const float* __restrict__ wz, const float* __restrict__ bz,
    float* __restrict__ out){
  __shared__ __align__(16) u16 Ah[256*128];    // 64 KB: xa then h (both swizzled)
  __shared__ __align__(16) u16 W2s[128*128];   // 32 KB
  __shared__ __align__(16) u16 Wcs[80*128];    // 20 KB
  __shared__ float b2s[128];
  __shared__ float bcs[80];

  const int blk = blockIdx.x;
  const int b   = blk >> 5, oy = blk & 31;
  const int t    = threadIdx.x;
  const int lane = t & 63;
  const int w    = t >> 6;              // wave = rotation r

  // ---- stage xa = leaky(ys + b1) -> Ah (swizzled bf16) ----
  {
    const int kn0 = (t & 15)*8;
    const int r_  = (t >> 4) & 7;
    float b1v[8];
#pragma unroll
    for (int j = 0; j < 8; ++j) b1v[j] = b1[kn0 + j];
#pragma unroll
    for (int i = 0; i < 8; ++i){
      int m_loc = 4*i + (t >> 7);       // 0..31 == ox
      int row_m = (((b >> 2)*32 + m_loc)*128) + (b & 3)*32 + oy;   // gemm m-mapping
      uint4 v = *(const uint4*)(ys + (size_t)row_m*1024 + r_*128 + kn0);
      u32 vv[4] = {v.x, v.y, v.z, v.w};
      u16 hh[8];
#pragma unroll
      for (int j = 0; j < 4; ++j){
        float lo = __uint_as_float(vv[j] << 16);
        float hi = __uint_as_float(vv[j] & 0xFFFF0000u);
        hh[2*j]   = f2bf(leaky_(lo + b1v[2*j]));
        hh[2*j+1] = f2bf(leaky_(hi + b1v[2*j+1]));
      }
      int Arow = r_*32 + m_loc;
      int off = (Arow*256 + kn0*2) ^ ((Arow & 7) << 4);
      uint4 pk;
      pk.x = (u32)hh[0] | ((u32)hh[1] << 16);
      pk.y = (u32)hh[2] | ((u32)hh[3] << 16);
      pk.z = (u32)hh[4] | ((u32)hh[5] << 16);
      pk.w = (u32)hh[6] | ((u32)hh[7] << 16);
      *(uint4*)((char*)Ah + off) = pk;
    }
  }
  // ---- stage w2 -> W2s ----
#pragma unroll
  for (int i = 0; i < 4; ++i){
    int ch = i*512 + t;                 // 2048 chunks
    int row = ch >> 4, kn0 = (ch & 15)*8;
    const float* src = w2 + row*128 + kn0;
    u16 hh[8];
#pragma unroll
    for (int j = 0; j < 8; ++j) hh[j] = f2bf(src[j]);
    int off = (row*256 + kn0*2) ^ ((row & 7) << 4);
    uint4 pk;
    pk.x = (u32)hh[0] | ((u32)hh[1] << 16);
    pk.y = (u32)hh[2] | ((u32)hh[3] << 16);
    pk.z = (u32)hh[4] | ((u32)hh[5] << 16);
    pk.w = (u32)hh[6] | ((u32)hh[7] << 16);
    *(uint4*)((char*)W2s + off) = pk;
  }
  // ---- stage Wcat -> Wcs : rows 0..63 wz, 64 wa, 65/66 wr, 67..79 zero ----
#pragma unroll
  for (int i = 0; i < 3; ++i){
    int ch = i*512 + t;                 // 1280 chunks
    if (ch < 1280){
      int row = ch >> 4, kn0 = (ch & 15)*8;
      const float* src = nullptr;
      if (row < 64)      src = wz + row*128 + kn0;
      else if (row == 64) src = wa + kn0;
      else if (row == 65) src = wr + kn0;
      else if (row == 66) src = wr + 128 + kn0;
      u16 hh[8];
#pragma unroll
      for (int j = 0; j < 8; ++j) hh[j] = src ? f2bf(src[j]) : (u16)0;
      int off = (row*256 + kn0*2) ^ ((row & 7) << 4);
      uint4 pk;
      pk.x = (u32)hh[0] | ((u32)hh[1] << 16);
      pk.y = (u32)hh[2] | ((u32)hh[3] << 16);
      pk.z = (u32)hh[4] | ((u32)hh[5] << 16);
      pk.w = (u32)hh[6] | ((u32)hh[7] << 16);
      *(uint4*)((char*)Wcs + off) = pk;
    }
  }
  if (t < 128) b2s[t] = b2[t];
  if (t < 80){
    float v = 0.0f;
    if (t < 64) v = bz[t];
    else if (t == 64) v = ba[0];
    else if (t == 65) v = br[0];
    else if (t == 66) v = br[1];
    bcs[t] = v;
  }
  __syncthreads();

  // ---- GEMM1: h_pre = xa @ w2^T, wave w handles rows w*32..w*32+31 ----
  f32x4 acc1[2][8];
#pragma unroll
  for (int mf = 0; mf < 2; ++mf)
#pragma unroll
    for (int nf = 0; nf < 8; ++nf) acc1[mf][nf] = (f32x4){0.f,0.f,0.f,0.f};
#pragma unroll
  for (int kk = 0; kk < 128; kk += 32){
    int kb = (kk + ((lane >> 4) << 3))*2;
    bf16x8 a[2], bv[8];
#pragma unroll
    for (int mf = 0; mf < 2; ++mf){
      int row = w*32 + mf*16 + (lane & 15);
      int off = (row*256 + kb) ^ ((row & 7) << 4);
      a[mf] = *(const bf16x8*)((const char*)Ah + off);
    }
#pragma unroll
    for (int nf = 0; nf < 8; ++nf){
      int row = nf*16 + (lane & 15);
      int off = (row*256 + kb) ^ ((row & 7) << 4);
      bv[nf] = *(const bf16x8*)((const char*)W2s + off);
    }
#pragma unroll
    for (int mf = 0; mf < 2; ++mf)
#pragma unroll
      for (int nf = 0; nf < 8; ++nf)
        acc1[mf][nf] = __builtin_amdgcn_mfma_f32_16x16x32_bf16(a[mf], bv[nf], acc1[mf][nf], 0, 0, 0);
  }
  __syncthreads();   // all waves done reading Ah

  // ---- h = leaky(h_pre + b2) -> overwrite Ah (bf16, swizzled) ----
#pragma unroll
  for (int mf = 0; mf < 2; ++mf)
#pragma unroll
    for (int nf = 0; nf < 8; ++nf){
      int col = nf*16 + (lane & 15);
      float bb = b2s[col];
#pragma unroll
      for (int j = 0; j < 4; ++j){
        int row = w*32 + mf*16 + ((lane >> 4) << 2) + j;
        u16 hv = f2bf(leaky_(acc1[mf][nf][j] + bb));
        int off = (row*256 + col*2) ^ ((row & 7) << 4);
        *(u16*)((char*)Ah + off) = hv;
      }
    }
  __syncthreads();

  // ---- GEMM2: outs = h @ Wcat^T ----
  f32x4 acc2[2][5];
#pragma unroll
  for (int mf = 0; mf < 2; ++mf)
#pragma unroll
    for (int nf = 0; nf < 5; ++nf) acc2[mf][nf] = (f32x4){0.f,0.f,0.f,0.f};
#pragma unroll
  for (int kk = 0; kk < 128; kk += 32){
    int kb = (kk + ((lane >> 4) << 3))*2;
    bf16x8 a[2], bv[5];
#pragma unroll
    for (int mf = 0; mf < 2; ++mf){
      int row = w*32 + mf*16 + (lane & 15);
      int off = (row*256 + kb) ^ ((row & 7) << 4);
      a[mf] = *(const bf16x8*)((const char*)Ah + off);
    }
#pragma unroll
    for (int nf = 0; nf < 5; ++nf){
      int row = nf*16 + (lane & 15);
      int off = (row*256 + kb) ^ ((row & 7) << 4);
      bv[nf] = *(const bf16x8*)((const char*)Wcs + off);
    }
#pragma unroll
    for (int mf = 0; mf < 2; ++mf)
#pragma unroll
      for (int nf = 0; nf < 5; ++nf)
        acc2[mf][nf] = __builtin_amdgcn_mfma_f32_16x16x32_bf16(a[mf], bv[nf], acc2[mf][nf], 0, 0, 0);
  }

  // ---- epilogue: fused bias / p_r / offsets, direct stores ----
  const int r = w;
  float off_r = OFFS[r];
  float qn = off_r / 3.14159265358979323846f;
  float pr = -0.5f*qn*qn - 1.14472988584940017414f - 0.91893853320467274178f;
  const int pixb = oy*32;
#pragma unroll
  for (int mf = 0; mf < 2; ++mf)
#pragma unroll
    for (int nf = 0; nf < 5; ++nf){
      int c = nf*16 + (lane & 15);
#pragma unroll
      for (int j = 0; j < 4; ++j){
        int ox = mf*16 + ((lane >> 4) << 2) + j;
        float val = acc2[mf][nf][j];
        if (c < 64){
          out[OUT_Z + (size_t)b*524288 + (size_t)c*8192 + r*1024 + pixb + ox] = val + bcs[c];
        } else if (c == 64){
          out[OUT_ATTN + (size_t)(b*8 + r)*1024 + pixb + ox] = val + bcs[64] + pr;
        } else if (c == 65){
          out[OUT_TH + ((size_t)b*2)*8192 + r*1024 + pixb + ox] = val + bcs[65] + off_r;
        } else if (c == 66){
          out[OUT_TH + ((size_t)b*2 + 1)*8192 + r*1024 + pixb + ox] = val + bcs[66];
        }
      }
    }
}

// ---------------- softmax: per batch b, over 8192 attn values ----------------
__global__ __launch_bounds__(256) void softmax_kernel(const float* __restrict__ gumbel, float* __restrict__ out){
  __shared__ float a[8192];
  __shared__ float red[256];
  const int b = blockIdx.x, t = threadIdx.x;
  const float* attn = out + OUT_ATTN + (size_t)b*8192;
  float m = -3.0e38f;
  for (int i = t; i < 8192; i += 256){ float v = attn[i]; a[i] = v; m = fmaxf(m, v); }
  red[t] = m; __syncthreads();
#pragma unroll
  for (int s = 128; s > 0; s >>= 1){ if (t < s) red[t] = fmaxf(red[t], red[t+s]); __syncthreads(); }
  m = red[0]; __syncthreads();
  float s1 = 0.0f;
  for (int i = t; i < 8192; i += 256) s1 += expf(a[i] - m);
  red[t] = s1; __syncthreads();
#pragma unroll
  for (int s = 128; s > 0; s >>= 1){ if (t < s) red[t] += red[t+s]; __syncthreads(); }
  float lse = m + logf(red[0]);
  __syncthreads();
  float* q = out + OUT_QTR + (size_t)b*8192;
  for (int i = t; i < 8192; i += 256) q[i] = a[i] - lse;
  const float* g = gumbel + (size_t)b*8192;
  float m2 = -3.0e38f;
  for (int i = t; i < 8192; i += 256){ float v = a[i] + g[i]; a[i] = v; m2 = fmaxf(m2, v); }
  __syncthreads();
  red[t] = m2; __syncthreads();
#pragma unroll
  for (int s = 128; s > 0; s >>= 1){ if (t < s) red[t] = fmaxf(red[t], red[t+s]); __syncthreads(); }
  m2 = red[0]; __syncthreads();
  float s2 = 0.0f;
  for (int i = t; i < 8192; i += 256) s2 += expf(a[i] - m2);
  red[t] = s2; __syncthreads();
#pragma unroll
  for (int s = 128; s > 0; s >>= 1){ if (t < s) red[t] += red[t+s]; __syncthreads(); }
  float inv = 1.0f/red[0];
  float* as_ = out + OUT_AS + (size_t)b*8192;
  for (int i = t; i < 8192; i += 256) as_[i] = expf(a[i] - m2)*inv;
}

// ---------------- tiny: p_r and offsets ----------------
__global__ void tiny_kernel(float* __restrict__ out){
  int t = threadIdx.x;
  if (t < 8){
    float off = OFFS[t];
    out[OUT_OFF + t] = off;
    float qn = off / 3.14159265358979323846f;
    out[OUT_PR + t] = -0.5f*qn*qn - 1.14472988584940017414f - 0.91893853320467274178f;
  }
}

extern "C" void kernel_launch(void* const* d_in, const int* in_sizes, int n_in,
                              void* d_out, int out_size, void* d_ws, size_t ws_size,
                              hipStream_t stream){
  const float* x      = (const float*)d_in[0];
  const float* w1     = (const float*)d_in[1];
  const float* b1     = (const float*)d_in[2];
  const float* w2     = (const float*)d_in[3];
  const float* b2     = (const float*)d_in[4];
  const float* wa     = (const float*)d_in[5];
  const float* ba     = (const float*)d_in[6];
  const float* wr     = (const float*)d_in[7];
  const float* br     = (const float*)d_in[8];
  const float* wz     = (const float*)d_in[9];
  const float* bz     = (const float*)d_in[10];
  const float* gumbel = (const float*)d_in[11];
  float* out = (float*)d_out;

  // workspace layout (bytes):
  // twb : 1024*4736*2      =  9,699,328
  // xsh : 8*32*96*128*2    =  6,291,456
  // ys  : 32768*1024*2     = 67,108,864
  u16* twb = (u16*)d_ws;
  u16* xsh = twb + (size_t)1024*KPAD;
  u16* ys  = xsh + (size_t)8*32*96*128;

  xshift_kernel <<<1536, 256, 0, stream>>>(x, xsh);
  rotate_kernel <<<1024, 256, 0, stream>>>(w1, twb);
  gemm_kernel   <<<512,  512, 0, stream>>>(xsh, twb, ys);
  mix_kernel    <<<1024, 512, 0, stream>>>(ys, b1, w2, b2, wa, ba, wr, br, wz, bz, out);
  softmax_kernel<<<32,   256, 0, stream>>>(gumbel, out);
  tiny_kernel   <<<1,    64,  0, stream>>>(out);
}